// Round 3
// baseline (797.160 us; speedup 1.0000x reference)
//
#include <hip/hip_runtime.h>
#include <stdint.h>
#include <math.h>

// Problem constants (B=2,S=2048,H=1024,E=8,K=2,F=4096)
#define T_TOK 4096
#define H_DIM 1024
#define E_EXP 8
#define F_DIM 4096
#define NASSIGN (T_TOK * 2)
#define OUT_ELEMS ((size_t)T_TOK * H_DIM)

typedef unsigned short u16;
typedef __attribute__((ext_vector_type(8))) short short8;   // 8 bf16 = 4 VGPRs
typedef __attribute__((ext_vector_type(4))) float f32x4;

__device__ __forceinline__ u16 f2bf(float f) {
  union { float f; uint32_t u; } c; c.f = f;
  uint32_t u = c.u;
  return (u16)((u + 0x7FFFu + ((u >> 16) & 1u)) >> 16);  // RNE
}

// async global->LDS, 16B per lane. LDS dest is wave-uniform base + lane*16.
__device__ __forceinline__ void gl_lds16(const void* g, void* l) {
  __builtin_amdgcn_global_load_lds(
      (const __attribute__((address_space(1))) uint32_t*)g,
      (__attribute__((address_space(3))) uint32_t*)(uintptr_t)l, 16, 0, 0);
}

// ---------------- weight convert+transpose to tiled layout ----------------
// in: [E][R][C] fp32 (R = K-dim, C = N-dim)
// out: [E][C/64][R/64][64][64] bf16, inner tile [c-local][r-local], r contiguous.
// Reads 256B segments, writes each 8KB tile fully contiguous.
__global__ __launch_bounds__(256) void transpose_cvt_tiled(
    const float* __restrict__ in, u16* __restrict__ out, int R, int C) {
  __shared__ u16 tile[64][72];  // pad to break store-gather conflicts
  const size_t eoff = (size_t)blockIdx.z * R * C;
  {
    const int c4 = (threadIdx.x & 15) * 4;
    const int rr = threadIdx.x >> 4;
    const float* inp = in + eoff + ((size_t)blockIdx.y * 64) * C + blockIdx.x * 64;
#pragma unroll
    for (int p = 0; p < 4; ++p) {
      const int r = rr + p * 16;
      const float4 v = *(const float4*)(inp + (size_t)r * C + c4);
      tile[r][c4 + 0] = f2bf(v.x); tile[r][c4 + 1] = f2bf(v.y);
      tile[r][c4 + 2] = f2bf(v.z); tile[r][c4 + 3] = f2bf(v.w);
    }
  }
  __syncthreads();
  {
    u16* op = out + (((size_t)blockIdx.z * (C >> 6) + blockIdx.x) * (R >> 6)
                     + blockIdx.y) * 4096;
#pragma unroll
    for (int p = 0; p < 2; ++p) {
      const int c = (threadIdx.x >> 3) + p * 32;
      const int rg = (threadIdx.x & 7) * 8;
      short8 o;
#pragma unroll
      for (int j = 0; j < 8; ++j) o[j] = (short)tile[rg + j][c];
      *(short8*)(op + c * 64 + rg) = o;
    }
  }
}

// ---------------- router (fused x fp32->bf16 conversion) ----------------
__global__ void router_kernel(const float* __restrict__ x, const float* __restrict__ Wr,
                              const float* __restrict__ br, u16* __restrict__ xb,
                              int* __restrict__ tki, float* __restrict__ tkw,
                              int* __restrict__ counts, float* __restrict__ zsum) {
  const int wave = threadIdx.x >> 6;
  const int lane = threadIdx.x & 63;
  const int t = blockIdx.x * 4 + wave;
  const float* xr = x + (size_t)t * H_DIM;
  u16* xbr = xb + (size_t)t * H_DIM;
  float acc[8];
#pragma unroll
  for (int e = 0; e < 8; ++e) acc[e] = 0.0f;
#pragma unroll
  for (int j = 0; j < 16; ++j) {
    const int hh = j * 64 + lane;
    const float xv = xr[hh];
    xbr[hh] = f2bf(xv);
    const float4 w0 = *(const float4*)(Wr + (size_t)hh * 8);
    const float4 w1 = *(const float4*)(Wr + (size_t)hh * 8 + 4);
    acc[0] += xv * w0.x; acc[1] += xv * w0.y; acc[2] += xv * w0.z; acc[3] += xv * w0.w;
    acc[4] += xv * w1.x; acc[5] += xv * w1.y; acc[6] += xv * w1.z; acc[7] += xv * w1.w;
  }
#pragma unroll
  for (int e = 0; e < 8; ++e) {
    float v = acc[e];
#pragma unroll
    for (int s = 32; s > 0; s >>= 1) v += __shfl_xor(v, s);
    acc[e] = v;
  }
  if (lane == 0) {
    float l[8];
#pragma unroll
    for (int e = 0; e < 8; ++e) l[e] = acc[e] + br[e];
    float mx = l[0];
#pragma unroll
    for (int e = 1; e < 8; ++e) mx = fmaxf(mx, l[e]);
    float p[8], s = 0.0f;
#pragma unroll
    for (int e = 0; e < 8; ++e) { p[e] = __expf(l[e] - mx); s += p[e]; }
    int i0 = 0;
#pragma unroll
    for (int e = 1; e < 8; ++e) if (p[e] > p[i0]) i0 = e;
    int i1 = (i0 == 0) ? 1 : 0;
#pragma unroll
    for (int e = 0; e < 8; ++e) if (e != i1 && e != i0 && p[e] > p[i1]) i1 = e;
    const float ws = p[i0] + p[i1];
    tki[2 * t] = i0; tki[2 * t + 1] = i1;
    tkw[2 * t] = p[i0] / ws; tkw[2 * t + 1] = p[i1] / ws;
    atomicAdd(&counts[i0], 1);
    atomicAdd(&counts[i1], 1);
    atomicAdd(zsum, mx + logf(s));
  }
}

__global__ void prefix_kernel(const int* __restrict__ counts, int* __restrict__ offs) {
  if (threadIdx.x == 0) {
    int a = 0;
#pragma unroll
    for (int e = 0; e < 8; ++e) { offs[e] = a; a += counts[e]; }
  }
}

__global__ void scatter_kernel(const int* __restrict__ tki, const float* __restrict__ tkw,
                               const int* __restrict__ offs, int* __restrict__ cursor,
                               int* __restrict__ perm, float* __restrict__ pw) {
  const int t = blockIdx.x * 256 + threadIdx.x;
#pragma unroll
  for (int k = 0; k < 2; ++k) {
    const int e = tki[2 * t + k];
    const int p = atomicAdd(&cursor[e], 1);
    perm[offs[e] + p] = t;
    pw[offs[e] + p] = tkw[2 * t + k];
  }
}

// ---------------- grouped GEMMs: 128x128 tile, BK=64, XOR-swizzled staging ----------------
// Swizzle: lane (tid) stages k-chunk ((tid&7) ^ (rbase&7)) of row rbase+l*32, so
// LDS row r holds its k-chunk j at slot j^(r&7). Fragment ds_read_b128 then spreads
// lanes over 8 bank-quads -> conflict-free (2-way aliasing only, which is free).

// h[slot][F] = gelu( xb[perm[slot]] @ W1t[e]^T + b1[e] )  (bf16 out)
__global__ __launch_bounds__(256, 4) void gemm1_kernel(
    const u16* __restrict__ xb, const u16* __restrict__ w1t,
    const float* __restrict__ b1, const int* __restrict__ perm,
    const int* __restrict__ cnts, const int* __restrict__ offs,
    u16* __restrict__ hbuf) {
  const int e = blockIdx.z;
  const int cnt = cnts[e];
  const int m0 = blockIdx.y * 128;
  if (m0 >= cnt) return;
  const int off = offs[e];
  const int n0 = blockIdx.x * 128;

  __shared__ __align__(16) u16 As[128 * 64];
  __shared__ __align__(16) u16 Bs[128 * 64];

  const int tid = threadIdx.x;
  const int rbase = tid >> 3;                       // 0..31
  const int kc = ((tid & 7) ^ (rbase & 7)) * 8;     // swizzled k-chunk offset (elems)

  const u16* ap[4];
#pragma unroll
  for (int l = 0; l < 4; ++l) {
    int ra = m0 + rbase + l * 32; if (ra > cnt - 1) ra = cnt - 1;
    ap[l] = xb + (size_t)perm[off + ra] * H_DIM + kc;
  }
  // B tiles: [E][F/64][H/64][64*64]
  const u16* bp0 = w1t + ((((size_t)e * (F_DIM >> 6) + (n0 >> 6)) * (H_DIM >> 6)) << 12)
                 + rbase * 64 + kc;
  const size_t bnt = (size_t)(H_DIM >> 6) << 12;    // next n-tile stride (elems)

  const int wave = tid >> 6, lane = tid & 63;
  const int wm = (wave >> 1) * 64, wn = (wave & 1) * 64;
  const int lr = lane & 15, q = lane >> 4;
  const int qs0 = q ^ (lr & 7), qs1 = (4 + q) ^ (lr & 7);

  f32x4 acc[4][4];
#pragma unroll
  for (int i = 0; i < 4; ++i)
#pragma unroll
    for (int j = 0; j < 4; ++j) acc[i][j] = (f32x4)0.0f;

  const short8* Afr = (const short8*)As;
  const short8* Bfr = (const short8*)Bs;

  for (int k0 = 0; k0 < (H_DIM >> 6); ++k0) {
    gl_lds16(ap[0], &As[(size_t)tid * 8]);
    gl_lds16(ap[1], &As[(size_t)(tid + 256) * 8]);
    gl_lds16(ap[2], &As[(size_t)(tid + 512) * 8]);
    gl_lds16(ap[3], &As[(size_t)(tid + 768) * 8]);
    gl_lds16(bp0,              &Bs[(size_t)tid * 8]);
    gl_lds16(bp0 + 2048,       &Bs[(size_t)(tid + 256) * 8]);
    gl_lds16(bp0 + bnt,        &Bs[(size_t)(tid + 512) * 8]);
    gl_lds16(bp0 + bnt + 2048, &Bs[(size_t)(tid + 768) * 8]);
#pragma unroll
    for (int l = 0; l < 4; ++l) ap[l] += 64;
    bp0 += 4096;
    __syncthreads();
#pragma unroll
    for (int s = 0; s < 2; ++s) {
      const int qs = s ? qs1 : qs0;
      short8 a[4], b[4];
#pragma unroll
      for (int i = 0; i < 4; ++i) a[i] = Afr[(wm + i * 16 + lr) * 8 + qs];
#pragma unroll
      for (int j = 0; j < 4; ++j) b[j] = Bfr[(wn + j * 16 + lr) * 8 + qs];
#pragma unroll
      for (int i = 0; i < 4; ++i)
#pragma unroll
        for (int j = 0; j < 4; ++j)
          acc[i][j] = __builtin_amdgcn_mfma_f32_16x16x32_bf16(a[i], b[j], acc[i][j], 0, 0, 0);
    }
    __syncthreads();
  }

#pragma unroll
  for (int i = 0; i < 4; ++i) {
#pragma unroll
    for (int rr = 0; rr < 4; ++rr) {
      const int m = m0 + wm + i * 16 + q * 4 + rr;
      if (m < cnt) {
        u16* hrow = hbuf + (size_t)(off + m) * F_DIM;
#pragma unroll
        for (int j = 0; j < 4; ++j) {
          const int col = n0 + wn + j * 16 + lr;
          const float v = acc[i][j][rr] + b1[e * F_DIM + col];
          const float g = 0.5f * v * (1.0f + erff(v * 0.70710678118654752f));
          hrow[col] = f2bf(g);
        }
      }
    }
  }
}

// out[token] += w * (h[slot] @ W2t[e]^T + b2[e])   -- split-K over 2 chunks
__global__ __launch_bounds__(256, 4) void gemm2_kernel(
    const u16* __restrict__ hbuf, const u16* __restrict__ w2t,
    const float* __restrict__ b2, const int* __restrict__ perm,
    const float* __restrict__ pw, const int* __restrict__ cnts,
    const int* __restrict__ offs, float* __restrict__ out) {
  const int ez = blockIdx.z;
  const int e = ez >> 1;
  const int ks = ez & 1;
  const int cnt = cnts[e];
  const int m0 = blockIdx.y * 128;
  if (m0 >= cnt) return;
  const int off = offs[e];
  const int n0 = blockIdx.x * 128;

  __shared__ __align__(16) u16 As[128 * 64];
  __shared__ __align__(16) u16 Bs[128 * 64];

  const int tid = threadIdx.x;
  const int rbase = tid >> 3;
  const int kc = ((tid & 7) ^ (rbase & 7)) * 8;

  const u16* ap[4];
#pragma unroll
  for (int l = 0; l < 4; ++l) {
    int ra = m0 + rbase + l * 32; if (ra > cnt - 1) ra = cnt - 1;
    ap[l] = hbuf + (size_t)(off + ra) * F_DIM + ks * 2048 + kc;
  }
  // B tiles: [E][H/64][F/64][64*64]
  const u16* bp0 = w2t + ((((size_t)e * (H_DIM >> 6) + (n0 >> 6)) * (F_DIM >> 6)
                           + ks * 32) << 12)
                 + rbase * 64 + kc;
  const size_t bnt = (size_t)(F_DIM >> 6) << 12;

  const int wave = tid >> 6, lane = tid & 63;
  const int wm = (wave >> 1) * 64, wn = (wave & 1) * 64;
  const int lr = lane & 15, q = lane >> 4;
  const int qs0 = q ^ (lr & 7), qs1 = (4 + q) ^ (lr & 7);

  f32x4 acc[4][4];
#pragma unroll
  for (int i = 0; i < 4; ++i)
#pragma unroll
    for (int j = 0; j < 4; ++j) acc[i][j] = (f32x4)0.0f;

  const short8* Afr = (const short8*)As;
  const short8* Bfr = (const short8*)Bs;

  for (int k0 = 0; k0 < (F_DIM >> 7); ++k0) {   // 2048/64 = 32 iters
    gl_lds16(ap[0], &As[(size_t)tid * 8]);
    gl_lds16(ap[1], &As[(size_t)(tid + 256) * 8]);
    gl_lds16(ap[2], &As[(size_t)(tid + 512) * 8]);
    gl_lds16(ap[3], &As[(size_t)(tid + 768) * 8]);
    gl_lds16(bp0,              &Bs[(size_t)tid * 8]);
    gl_lds16(bp0 + 2048,       &Bs[(size_t)(tid + 256) * 8]);
    gl_lds16(bp0 + bnt,        &Bs[(size_t)(tid + 512) * 8]);
    gl_lds16(bp0 + bnt + 2048, &Bs[(size_t)(tid + 768) * 8]);
#pragma unroll
    for (int l = 0; l < 4; ++l) ap[l] += 64;
    bp0 += 4096;
    __syncthreads();
#pragma unroll
    for (int s = 0; s < 2; ++s) {
      const int qs = s ? qs1 : qs0;
      short8 a[4], b[4];
#pragma unroll
      for (int i = 0; i < 4; ++i) a[i] = Afr[(wm + i * 16 + lr) * 8 + qs];
#pragma unroll
      for (int j = 0; j < 4; ++j) b[j] = Bfr[(wn + j * 16 + lr) * 8 + qs];
#pragma unroll
      for (int i = 0; i < 4; ++i)
#pragma unroll
        for (int j = 0; j < 4; ++j)
          acc[i][j] = __builtin_amdgcn_mfma_f32_16x16x32_bf16(a[i], b[j], acc[i][j], 0, 0, 0);
    }
    __syncthreads();
  }

#pragma unroll
  for (int i = 0; i < 4; ++i) {
#pragma unroll
    for (int rr = 0; rr < 4; ++rr) {
      const int m = m0 + wm + i * 16 + q * 4 + rr;
      if (m < cnt) {
        const int slot = off + m;
        const int token = perm[slot];
        const float w = pw[slot];
        float* orow = out + (size_t)token * H_DIM;
#pragma unroll
        for (int j = 0; j < 4; ++j) {
          const int col = n0 + wn + j * 16 + lr;
          float y = acc[i][j][rr];
          if (ks == 0) y += b2[e * H_DIM + col];
          atomicAdd(&orow[col], w * y);
        }
      }
    }
  }
}

__global__ void loss_kernel(const int* __restrict__ counts, const float* __restrict__ zsum,
                            float* __restrict__ out_loss) {
  if (threadIdx.x == 0 && blockIdx.x == 0) {
    float aux = 0.0f;
#pragma unroll
    for (int e = 0; e < 8; ++e) {
      const float d = (float)counts[e] / (float)NASSIGN - 0.125f;
      aux += d * d;
    }
    aux *= (1.0f / 8.0f);
    const float z = zsum[0] / (float)T_TOK;
    out_loss[0] = 0.01f * aux + 0.001f * z;
  }
}

// ---------------- launch ----------------

extern "C" void kernel_launch(void* const* d_in, const int* in_sizes, int n_in,
                              void* d_out, int out_size, void* d_ws, size_t ws_size,
                              hipStream_t stream) {
  const float* x  = (const float*)d_in[0];
  const float* Wr = (const float*)d_in[1];
  const float* br = (const float*)d_in[2];
  const float* W1 = (const float*)d_in[3];
  const float* b1 = (const float*)d_in[4];
  const float* W2 = (const float*)d_in[5];
  const float* b2 = (const float*)d_in[6];
  float* out = (float*)d_out;

  // workspace layout (~210 MB)
  char* ws = (char*)d_ws;
  u16* xb    = (u16*)(ws);                          // 8 MB
  u16* w1t   = (u16*)(ws + 8388608ull);             // 64 MB  tiled [E][F/64][H/64][64][64]
  u16* w2t   = (u16*)(ws + 75497472ull);            // 64 MB  tiled [E][H/64][F/64][64][64]
  u16* hbuf  = (u16*)(ws + 142606336ull);           // 64 MB  [8192][F] bf16
  int*   tki    = (int*)(ws + 209715200ull);
  float* tkw    = (float*)(ws + 209747968ull);
  int*   perm   = (int*)(ws + 209780736ull);
  float* pw     = (float*)(ws + 209813504ull);
  int*   counts = (int*)(ws + 209846272ull);        // counts[8], offs[8], cursor[8], zsum
  int*   offs   = counts + 8;
  int*   cursor = counts + 16;
  float* zsum   = (float*)(counts + 24);

  hipMemsetAsync(out, 0, (size_t)out_size * sizeof(float), stream);
  hipMemsetAsync(counts, 0, 128, stream);

  // W1 [E][H][F]: R=H(K), C=F(N) -> tiles [E][F/64][H/64]
  transpose_cvt_tiled<<<dim3(F_DIM / 64, H_DIM / 64, E_EXP), 256, 0, stream>>>(W1, w1t, H_DIM, F_DIM);
  // W2 [E][F][H]: R=F(K), C=H(N) -> tiles [E][H/64][F/64]
  transpose_cvt_tiled<<<dim3(H_DIM / 64, F_DIM / 64, E_EXP), 256, 0, stream>>>(W2, w2t, F_DIM, H_DIM);
  router_kernel<<<T_TOK / 4, 256, 0, stream>>>(x, Wr, br, xb, tki, tkw, counts, zsum);
  prefix_kernel<<<1, 64, 0, stream>>>(counts, offs);
  scatter_kernel<<<T_TOK / 256, 256, 0, stream>>>(tki, tkw, offs, cursor, perm, pw);
  gemm1_kernel<<<dim3(F_DIM / 128, T_TOK / 128, E_EXP), 256, 0, stream>>>(
      xb, w1t, b1, perm, counts, offs, hbuf);
  gemm2_kernel<<<dim3(H_DIM / 128, T_TOK / 128, E_EXP * 2), 256, 0, stream>>>(
      hbuf, w2t, b2, perm, pw, counts, offs, out);
  loss_kernel<<<1, 64, 0, stream>>>(counts, zsum, out + OUT_ELEMS);
}

// Round 4
// 762.291 us; speedup vs baseline: 1.0457x; 1.0457x over previous
//
#include <hip/hip_runtime.h>
#include <stdint.h>
#include <math.h>

// Problem constants (B=2,S=2048,H=1024,E=8,K=2,F=4096)
#define T_TOK 4096
#define H_DIM 1024
#define E_EXP 8
#define F_DIM 4096
#define NASSIGN (T_TOK * 2)
#define OUT_ELEMS ((size_t)T_TOK * H_DIM)

typedef unsigned short u16;
typedef __attribute__((ext_vector_type(8))) short short8;   // 8 bf16 = 4 VGPRs
typedef __attribute__((ext_vector_type(4))) float f32x4;

__device__ __forceinline__ u16 f2bf(float f) {
  union { float f; uint32_t u; } c; c.f = f;
  uint32_t u = c.u;
  return (u16)((u + 0x7FFFu + ((u >> 16) & 1u)) >> 16);  // RNE
}

// async global->LDS, 16B per lane. LDS dest is wave-uniform base + lane*16.
__device__ __forceinline__ void gl_lds16(const void* g, void* l) {
  __builtin_amdgcn_global_load_lds(
      (const __attribute__((address_space(1))) uint32_t*)g,
      (__attribute__((address_space(3))) uint32_t*)(uintptr_t)l, 16, 0, 0);
}

// ---------------- weight convert+transpose to tiled layout ----------------
// in: [E][R][C] fp32 (R = K-dim, C = N-dim)
// out: [E][C/64][R/64][64][64] bf16, inner tile [c-local][r-local], r contiguous.
__global__ __launch_bounds__(256) void transpose_cvt_tiled(
    const float* __restrict__ in, u16* __restrict__ out, int R, int C) {
  __shared__ u16 tile[64][72];
  const size_t eoff = (size_t)blockIdx.z * R * C;
  {
    const int c4 = (threadIdx.x & 15) * 4;
    const int rr = threadIdx.x >> 4;
    const float* inp = in + eoff + ((size_t)blockIdx.y * 64) * C + blockIdx.x * 64;
#pragma unroll
    for (int p = 0; p < 4; ++p) {
      const int r = rr + p * 16;
      const float4 v = *(const float4*)(inp + (size_t)r * C + c4);
      tile[r][c4 + 0] = f2bf(v.x); tile[r][c4 + 1] = f2bf(v.y);
      tile[r][c4 + 2] = f2bf(v.z); tile[r][c4 + 3] = f2bf(v.w);
    }
  }
  __syncthreads();
  {
    u16* op = out + (((size_t)blockIdx.z * (C >> 6) + blockIdx.x) * (R >> 6)
                     + blockIdx.y) * 4096;
#pragma unroll
    for (int p = 0; p < 2; ++p) {
      const int c = (threadIdx.x >> 3) + p * 32;
      const int rg = (threadIdx.x & 7) * 8;
      short8 o;
#pragma unroll
      for (int j = 0; j < 8; ++j) o[j] = (short)tile[rg + j][c];
      *(short8*)(op + c * 64 + rg) = o;
    }
  }
}

// ---------------- router (fused x fp32->bf16 conversion) ----------------
__global__ void router_kernel(const float* __restrict__ x, const float* __restrict__ Wr,
                              const float* __restrict__ br, u16* __restrict__ xb,
                              int* __restrict__ tki, float* __restrict__ tkw,
                              int* __restrict__ counts, float* __restrict__ zsum) {
  const int wave = threadIdx.x >> 6;
  const int lane = threadIdx.x & 63;
  const int t = blockIdx.x * 4 + wave;
  const float* xr = x + (size_t)t * H_DIM;
  u16* xbr = xb + (size_t)t * H_DIM;
  float acc[8];
#pragma unroll
  for (int e = 0; e < 8; ++e) acc[e] = 0.0f;
#pragma unroll
  for (int j = 0; j < 16; ++j) {
    const int hh = j * 64 + lane;
    const float xv = xr[hh];
    xbr[hh] = f2bf(xv);
    const float4 w0 = *(const float4*)(Wr + (size_t)hh * 8);
    const float4 w1 = *(const float4*)(Wr + (size_t)hh * 8 + 4);
    acc[0] += xv * w0.x; acc[1] += xv * w0.y; acc[2] += xv * w0.z; acc[3] += xv * w0.w;
    acc[4] += xv * w1.x; acc[5] += xv * w1.y; acc[6] += xv * w1.z; acc[7] += xv * w1.w;
  }
#pragma unroll
  for (int e = 0; e < 8; ++e) {
    float v = acc[e];
#pragma unroll
    for (int s = 32; s > 0; s >>= 1) v += __shfl_xor(v, s);
    acc[e] = v;
  }
  if (lane == 0) {
    float l[8];
#pragma unroll
    for (int e = 0; e < 8; ++e) l[e] = acc[e] + br[e];
    float mx = l[0];
#pragma unroll
    for (int e = 1; e < 8; ++e) mx = fmaxf(mx, l[e]);
    float p[8], s = 0.0f;
#pragma unroll
    for (int e = 0; e < 8; ++e) { p[e] = __expf(l[e] - mx); s += p[e]; }
    int i0 = 0;
#pragma unroll
    for (int e = 1; e < 8; ++e) if (p[e] > p[i0]) i0 = e;
    int i1 = (i0 == 0) ? 1 : 0;
#pragma unroll
    for (int e = 0; e < 8; ++e) if (e != i1 && e != i0 && p[e] > p[i1]) i1 = e;
    const float ws = p[i0] + p[i1];
    tki[2 * t] = i0; tki[2 * t + 1] = i1;
    tkw[2 * t] = p[i0] / ws; tkw[2 * t + 1] = p[i1] / ws;
    atomicAdd(&counts[i0], 1);
    atomicAdd(&counts[i1], 1);
    atomicAdd(zsum, mx + logf(s));
  }
}

// scatter + (block 0) loss. Each block computes the 8-wide prefix locally.
__global__ void scatter_kernel(const int* __restrict__ tki, const float* __restrict__ tkw,
                               const int* __restrict__ counts, int* __restrict__ cursor,
                               int* __restrict__ perm, float* __restrict__ pw,
                               const float* __restrict__ zsum, float* __restrict__ out_loss) {
  int offs[8];
  {
    int a = 0;
#pragma unroll
    for (int e = 0; e < 8; ++e) { offs[e] = a; a += counts[e]; }
  }
  const int t = blockIdx.x * 256 + threadIdx.x;
#pragma unroll
  for (int k = 0; k < 2; ++k) {
    const int e = tki[2 * t + k];
    const int p = atomicAdd(&cursor[e], 1);
    perm[offs[e] + p] = t;
    pw[offs[e] + p] = tkw[2 * t + k];
  }
  if (blockIdx.x == 0 && threadIdx.x == 0) {
    float aux = 0.0f;
#pragma unroll
    for (int e = 0; e < 8; ++e) {
      const float d = (float)counts[e] / (float)NASSIGN - 0.125f;
      aux += d * d;
    }
    aux *= (1.0f / 8.0f);
    out_loss[0] = 0.01f * aux + 0.001f * (zsum[0] / (float)T_TOK);
  }
}

// ---------------- grouped GEMMs: 128x128 tile, BK=64, XOR-swizzled staging ----------------
// Grid is 1D; id&7 = expert -> XCD (round-robin heuristic) so each expert's
// working set (A-stripe + B k-chunk, ~4MB) stays in one XCD's L2.

// h[slot][F] = gelu( xb[perm[slot]] @ W1t[e]^T + b1[e] )  (bf16 out)
__global__ __launch_bounds__(256, 4) void gemm1_kernel(
    const u16* __restrict__ xb, const u16* __restrict__ w1t,
    const float* __restrict__ b1, const int* __restrict__ perm,
    const int* __restrict__ cnts, u16* __restrict__ hbuf) {
  const int id = blockIdx.x;
  const int e = id & 7;               // XCD group
  const int wq = id >> 3;
  const int n0 = (wq & 31) << 7;      // 32 n-blocks
  const int m0 = (wq >> 5) << 7;      // m outer: live blocks dispatch first
  int cnt, off;
  {
    int a = 0, c = 0;
#pragma unroll
    for (int i = 0; i < 8; ++i) { const int ci = cnts[i]; if (i < e) a += ci; if (i == e) c = ci; }
    cnt = c; off = a;
  }
  if (m0 >= cnt) return;

  __shared__ __align__(16) u16 smem[16384];   // As 8192 + Bs 8192; epilogue reuses all 32KB
  u16* As = smem;
  u16* Bs = smem + 8192;

  const int tid = threadIdx.x;
  const int rbase = tid >> 3;
  const int kc = ((tid & 7) ^ (rbase & 7)) * 8;

  const u16* ap[4];
#pragma unroll
  for (int l = 0; l < 4; ++l) {
    int ra = m0 + rbase + l * 32; if (ra > cnt - 1) ra = cnt - 1;
    ap[l] = xb + (size_t)perm[off + ra] * H_DIM + kc;
  }
  const u16* bp0 = w1t + ((((size_t)e * (F_DIM >> 6) + (n0 >> 6)) * (H_DIM >> 6)) << 12)
                 + rbase * 64 + kc;
  const size_t bnt = (size_t)(H_DIM >> 6) << 12;

  const int wave = tid >> 6, lane = tid & 63;
  const int wm = (wave >> 1) * 64, wn = (wave & 1) * 64;
  const int lr = lane & 15, q = lane >> 4;
  const int qs0 = q ^ (lr & 7), qs1 = (4 + q) ^ (lr & 7);

  f32x4 acc[4][4];
#pragma unroll
  for (int i = 0; i < 4; ++i)
#pragma unroll
    for (int j = 0; j < 4; ++j) acc[i][j] = (f32x4)0.0f;

  const short8* Afr = (const short8*)As;
  const short8* Bfr = (const short8*)Bs;

  for (int k0 = 0; k0 < (H_DIM >> 6); ++k0) {
    gl_lds16(ap[0], &As[(size_t)tid * 8]);
    gl_lds16(ap[1], &As[(size_t)(tid + 256) * 8]);
    gl_lds16(ap[2], &As[(size_t)(tid + 512) * 8]);
    gl_lds16(ap[3], &As[(size_t)(tid + 768) * 8]);
    gl_lds16(bp0,              &Bs[(size_t)tid * 8]);
    gl_lds16(bp0 + 2048,       &Bs[(size_t)(tid + 256) * 8]);
    gl_lds16(bp0 + bnt,        &Bs[(size_t)(tid + 512) * 8]);
    gl_lds16(bp0 + bnt + 2048, &Bs[(size_t)(tid + 768) * 8]);
#pragma unroll
    for (int l = 0; l < 4; ++l) ap[l] += 64;
    bp0 += 4096;
    __syncthreads();
#pragma unroll
    for (int s = 0; s < 2; ++s) {
      const int qs = s ? qs1 : qs0;
      short8 a[4], b[4];
#pragma unroll
      for (int i = 0; i < 4; ++i) a[i] = Afr[(wm + i * 16 + lr) * 8 + qs];
#pragma unroll
      for (int j = 0; j < 4; ++j) b[j] = Bfr[(wn + j * 16 + lr) * 8 + qs];
#pragma unroll
      for (int i = 0; i < 4; ++i)
#pragma unroll
        for (int j = 0; j < 4; ++j)
          acc[i][j] = __builtin_amdgcn_mfma_f32_16x16x32_bf16(a[i], b[j], acc[i][j], 0, 0, 0);
    }
    __syncthreads();
  }

  // Epilogue: bias+gelu -> bf16 -> LDS (XOR col swizzle by row-quad) -> 16B stores.
#pragma unroll
  for (int i = 0; i < 4; ++i) {
#pragma unroll
    for (int rr = 0; rr < 4; ++rr) {
      const int row = wm + i * 16 + q * 4 + rr;
#pragma unroll
      for (int j = 0; j < 4; ++j) {
        const int col = wn + j * 16 + lr;
        const float v = acc[i][j][rr] + b1[e * F_DIM + n0 + col];
        const float g = 0.5f * v * (1.0f + erff(v * 0.70710678118654752f));
        smem[(row << 7) + (col ^ (q << 4))] = f2bf(g);
      }
    }
  }
  __syncthreads();
#pragma unroll
  for (int p = 0; p < 8; ++p) {
    const int ml = p * 16 + (tid >> 4);
    const int nl = (tid & 15) * 8;
    const int m = m0 + ml;
    if (m < cnt) {
      const int qq = (ml >> 2) & 3;
      *(short8*)(hbuf + (size_t)(off + m) * F_DIM + n0 + nl) =
          *(const short8*)(smem + (ml << 7) + (nl ^ (qq << 4)));
    }
  }
}

// out[token] += w * (h[slot] @ W2t[e]^T + b2[e])   -- split-K over 4 chunks
__global__ __launch_bounds__(256, 4) void gemm2_kernel(
    const u16* __restrict__ hbuf, const u16* __restrict__ w2t,
    const float* __restrict__ b2, const int* __restrict__ perm,
    const float* __restrict__ pw, const int* __restrict__ cnts,
    float* __restrict__ out) {
  const int id = blockIdx.x;
  const int e = id & 7;               // XCD group
  const int wq = id >> 3;
  const int n0 = (wq & 7) << 7;       // 8 n-blocks
  const int ks = (wq >> 3) & 3;       // 4 K-splits
  const int m0 = (wq >> 5) << 7;      // m outer
  int cnt, off;
  {
    int a = 0, c = 0;
#pragma unroll
    for (int i = 0; i < 8; ++i) { const int ci = cnts[i]; if (i < e) a += ci; if (i == e) c = ci; }
    cnt = c; off = a;
  }
  if (m0 >= cnt) return;

  __shared__ __align__(16) u16 As[128 * 64];
  __shared__ __align__(16) u16 Bs[128 * 64];

  const int tid = threadIdx.x;
  const int rbase = tid >> 3;
  const int kc = ((tid & 7) ^ (rbase & 7)) * 8;

  const u16* ap[4];
#pragma unroll
  for (int l = 0; l < 4; ++l) {
    int ra = m0 + rbase + l * 32; if (ra > cnt - 1) ra = cnt - 1;
    ap[l] = hbuf + (size_t)(off + ra) * F_DIM + (ks << 10) + kc;
  }
  const u16* bp0 = w2t + ((((size_t)e * (H_DIM >> 6) + (n0 >> 6)) * (F_DIM >> 6)
                           + (ks << 4)) << 12)
                 + rbase * 64 + kc;
  const size_t bnt = (size_t)(F_DIM >> 6) << 12;

  const int wave = tid >> 6, lane = tid & 63;
  const int wm = (wave >> 1) * 64, wn = (wave & 1) * 64;
  const int lr = lane & 15, q = lane >> 4;
  const int qs0 = q ^ (lr & 7), qs1 = (4 + q) ^ (lr & 7);

  f32x4 acc[4][4];
#pragma unroll
  for (int i = 0; i < 4; ++i)
#pragma unroll
    for (int j = 0; j < 4; ++j) acc[i][j] = (f32x4)0.0f;

  const short8* Afr = (const short8*)As;
  const short8* Bfr = (const short8*)Bs;

  for (int k0 = 0; k0 < 16; ++k0) {   // 1024 / 64
    gl_lds16(ap[0], &As[(size_t)tid * 8]);
    gl_lds16(ap[1], &As[(size_t)(tid + 256) * 8]);
    gl_lds16(ap[2], &As[(size_t)(tid + 512) * 8]);
    gl_lds16(ap[3], &As[(size_t)(tid + 768) * 8]);
    gl_lds16(bp0,              &Bs[(size_t)tid * 8]);
    gl_lds16(bp0 + 2048,       &Bs[(size_t)(tid + 256) * 8]);
    gl_lds16(bp0 + bnt,        &Bs[(size_t)(tid + 512) * 8]);
    gl_lds16(bp0 + bnt + 2048, &Bs[(size_t)(tid + 768) * 8]);
#pragma unroll
    for (int l = 0; l < 4; ++l) ap[l] += 64;
    bp0 += 4096;
    __syncthreads();
#pragma unroll
    for (int s = 0; s < 2; ++s) {
      const int qs = s ? qs1 : qs0;
      short8 a[4], b[4];
#pragma unroll
      for (int i = 0; i < 4; ++i) a[i] = Afr[(wm + i * 16 + lr) * 8 + qs];
#pragma unroll
      for (int j = 0; j < 4; ++j) b[j] = Bfr[(wn + j * 16 + lr) * 8 + qs];
#pragma unroll
      for (int i = 0; i < 4; ++i)
#pragma unroll
        for (int j = 0; j < 4; ++j)
          acc[i][j] = __builtin_amdgcn_mfma_f32_16x16x32_bf16(a[i], b[j], acc[i][j], 0, 0, 0);
    }
    __syncthreads();
  }

#pragma unroll
  for (int i = 0; i < 4; ++i) {
#pragma unroll
    for (int rr = 0; rr < 4; ++rr) {
      const int m = m0 + wm + i * 16 + q * 4 + rr;
      if (m < cnt) {
        const int slot = off + m;
        const int token = perm[slot];
        const float w = pw[slot];
        float* orow = out + (size_t)token * H_DIM;
#pragma unroll
        for (int j = 0; j < 4; ++j) {
          const int col = n0 + wn + j * 16 + lr;
          float y = acc[i][j][rr];
          if (ks == 0) y += b2[e * H_DIM + col];
          atomicAdd(&orow[col], w * y);
        }
      }
    }
  }
}

// ---------------- launch ----------------

extern "C" void kernel_launch(void* const* d_in, const int* in_sizes, int n_in,
                              void* d_out, int out_size, void* d_ws, size_t ws_size,
                              hipStream_t stream) {
  const float* x  = (const float*)d_in[0];
  const float* Wr = (const float*)d_in[1];
  const float* br = (const float*)d_in[2];
  const float* W1 = (const float*)d_in[3];
  const float* b1 = (const float*)d_in[4];
  const float* W2 = (const float*)d_in[5];
  const float* b2 = (const float*)d_in[6];
  float* out = (float*)d_out;

  // workspace layout (~210 MB)
  char* ws = (char*)d_ws;
  u16* xb    = (u16*)(ws);                          // 8 MB
  u16* w1t   = (u16*)(ws + 8388608ull);             // 64 MB  tiled [E][F/64][H/64][64][64]
  u16* w2t   = (u16*)(ws + 75497472ull);            // 64 MB  tiled [E][H/64][F/64][64][64]
  u16* hbuf  = (u16*)(ws + 142606336ull);           // 64 MB  [8192][F] bf16
  int*   tki    = (int*)(ws + 209715200ull);
  float* tkw    = (float*)(ws + 209747968ull);
  int*   perm   = (int*)(ws + 209780736ull);
  float* pw     = (float*)(ws + 209813504ull);
  int*   counts = (int*)(ws + 209846272ull);        // counts[8], cursor[8], zsum
  int*   cursor = counts + 8;
  float* zsum   = (float*)(counts + 16);

  hipMemsetAsync(out, 0, (size_t)out_size * sizeof(float), stream);
  hipMemsetAsync(counts, 0, 128, stream);

  // W1 [E][H][F]: R=H(K), C=F(N) -> tiles [E][F/64][H/64]
  transpose_cvt_tiled<<<dim3(F_DIM / 64, H_DIM / 64, E_EXP), 256, 0, stream>>>(W1, w1t, H_DIM, F_DIM);
  // W2 [E][F][H]: R=F(K), C=H(N) -> tiles [E][H/64][F/64]
  transpose_cvt_tiled<<<dim3(H_DIM / 64, F_DIM / 64, E_EXP), 256, 0, stream>>>(W2, w2t, F_DIM, H_DIM);
  router_kernel<<<T_TOK / 4, 256, 0, stream>>>(x, Wr, br, xb, tki, tkw, counts, zsum);
  scatter_kernel<<<T_TOK / 256, 256, 0, stream>>>(tki, tkw, counts, cursor, perm, pw,
                                                  zsum, out + OUT_ELEMS);
  gemm1_kernel<<<8192, 256, 0, stream>>>(xb, w1t, b1, perm, counts, hbuf);
  gemm2_kernel<<<8192, 256, 0, stream>>>(hbuf, w2t, b2, perm, pw, counts, out);
}